// Round 3
// baseline (290.677 us; speedup 1.0000x reference)
//
#include <hip/hip_runtime.h>

#define B_ 2048
#define T_ 200
#define D_ 64

constexpr int WAVES = 4;         // waves per block, 1 batch row per wave
constexpr int BLK = WAVES * 64;  // 256 threads
constexpr int NBLK = B_ / WAVES; // 512 blocks -> 2 per CU

typedef _Float16 half_t;
typedef __attribute__((ext_vector_type(2))) _Float16 h2;
typedef __attribute__((ext_vector_type(8))) _Float16 h8;

#if defined(__has_builtin)
#if __has_builtin(__builtin_amdgcn_fdot2)
#define HAS_FDOT2 1
#endif
#endif

__device__ __forceinline__ float dot2f(h2 a, h2 b, float c) {
#ifdef HAS_FDOT2
  return __builtin_amdgcn_fdot2(a, b, c, false);
#else
  return fmaf((float)a[0], (float)b[0], fmaf((float)a[1], (float)b[1], c));
#endif
}

// i is compile-time after unroll: h2 = i-th 32-bit register of the h8 tuple (free).
__device__ __forceinline__ h2 pick(h8 v, int i) {
  h2 r;
  r[0] = v[2 * i];
  r[1] = v[2 * i + 1];
  return r;
}

__device__ __forceinline__ float sigmoidf_(float x) {
  return 1.0f / (1.0f + __expf(-x));
}
__device__ __forceinline__ float tanhf_(float x) {
  x = fminf(fmaxf(x, -15.0f), 15.0f);
  float e = __expf(2.0f * x);
  return (e - 1.0f) / (e + 1.0f);
}

__global__ __launch_bounds__(BLK, 2) void augru_pipe(
    const float* __restrict__ X, const int* __restrict__ SL,
    const float* __restrict__ ATT, const float* __restrict__ Wg,
    const float* __restrict__ bg, const float* __restrict__ Wc,
    const float* __restrict__ bc, float* __restrict__ OUT) {
  // Per-wave broadcast scratch: [x(64) | h(64) | rh(64)] fp16.
  __shared__ __align__(16) half_t sV[WAVES][192];

  const int tid = threadIdx.x;
  const int wave = tid >> 6;
  const int d = tid & 63;
  const int b = blockIdx.x * WAVES + wave;

  // ---- Per-lane weight columns in VGPRs as fp16 pairs ----
  // k2 in [0,32): x rows; k2 in [32,64): h rows (gates input = concat([x,h])).
  h2 wr[64], wu[64], wc[64];
#pragma unroll
  for (int k2 = 0; k2 < 64; ++k2) {
    h2 v;
    v[0] = (half_t)Wg[(2 * k2) * 128 + d];
    v[1] = (half_t)Wg[(2 * k2 + 1) * 128 + d];
    wr[k2] = v;
    v[0] = (half_t)Wg[(2 * k2) * 128 + 64 + d];
    v[1] = (half_t)Wg[(2 * k2 + 1) * 128 + 64 + d];
    wu[k2] = v;
    v[0] = (half_t)Wc[(2 * k2) * 64 + d];
    v[1] = (half_t)Wc[(2 * k2 + 1) * 64 + d];
    wc[k2] = v;
  }

  const float bgr = bg[d];
  const float bgu = bg[64 + d];
  const float bcd = bc[d];

  const int L = SL[b];  // >= 1 per reference
  const float* __restrict__ xrow = X + (size_t)b * (T_ * D_);
  const float* __restrict__ arow = ATT + (size_t)b * T_;
  float* __restrict__ orow = OUT + (size_t)b * (T_ * D_);

  half_t* __restrict__ vx = &sV[wave][0];
  half_t* __restrict__ vhh = &sV[wave][64];
  half_t* __restrict__ vrh = &sV[wave][128];
  const h8* __restrict__ px = (const h8*)vx;
  const h8* __restrict__ ph = (const h8*)vhh;
  const h8* __restrict__ pr = (const h8*)vrh;

  float h = 0.0f;

  // ---- Prologue: x-contributions for t=0 ----
  vx[d] = (half_t)xrow[d];
  asm volatile("" ::: "memory");
  float arx, aux, acx;
  {
    float r0 = bgr, r1 = 0.f, u0 = bgu, u1 = 0.f, c0 = bcd, c1 = 0.f;
#pragma unroll
    for (int q = 0; q < 8; ++q) {
      const h8 xb = px[q];
      r0 = dot2f(pick(xb, 0), wr[4 * q + 0], r0);
      r1 = dot2f(pick(xb, 1), wr[4 * q + 1], r1);
      r0 = dot2f(pick(xb, 2), wr[4 * q + 2], r0);
      r1 = dot2f(pick(xb, 3), wr[4 * q + 3], r1);
      u0 = dot2f(pick(xb, 0), wu[4 * q + 0], u0);
      u1 = dot2f(pick(xb, 1), wu[4 * q + 1], u1);
      u0 = dot2f(pick(xb, 2), wu[4 * q + 2], u0);
      u1 = dot2f(pick(xb, 3), wu[4 * q + 3], u1);
      c0 = dot2f(pick(xb, 0), wc[4 * q + 0], c0);
      c1 = dot2f(pick(xb, 1), wc[4 * q + 1], c1);
      c0 = dot2f(pick(xb, 2), wc[4 * q + 2], c0);
      c1 = dot2f(pick(xb, 3), wc[4 * q + 3], c1);
    }
    arx = r0 + r1;
    aux = u0 + u1;
    acx = c0 + c1;
  }

  float xn = xrow[((1 < L) ? 1 : (L - 1)) * D_ + d];  // x_{t+1} (clamped)
  float an = arow[0];                                  // a_t

  for (int t = 0; t < L; ++t) {
    // Stage h_t and x_{t+1}; DS pipe is in-order within a wave -> no hard drain.
    vhh[d] = (half_t)h;
    vx[d] = (half_t)xn;
    asm volatile("" ::: "memory");

    // Global prefetch for later steps (independent of this step's chain).
    const int t2 = (t + 2 < L) ? t + 2 : (L - 1);
    const float xn2 = xrow[t2 * D_ + d];
    const int t1 = (t + 1 < L) ? t + 1 : (L - 1);
    const float an1 = arow[t1];

    // ---- Phase A: gate h-part (serial-critical) interleaved with
    //      next step's gate x-part (independent filler). 2 sub-chains each.
    float ar0 = arx, ar1 = 0.f, au0 = aux, au1 = 0.f;
    float nr0 = bgr, nr1 = 0.f, nu0 = bgu, nu1 = 0.f;
#pragma unroll
    for (int q = 0; q < 8; ++q) {
      const h8 hb = ph[q];
      const h8 xb = px[q];
      ar0 = dot2f(pick(hb, 0), wr[32 + 4 * q + 0], ar0);
      ar1 = dot2f(pick(hb, 1), wr[32 + 4 * q + 1], ar1);
      ar0 = dot2f(pick(hb, 2), wr[32 + 4 * q + 2], ar0);
      ar1 = dot2f(pick(hb, 3), wr[32 + 4 * q + 3], ar1);
      au0 = dot2f(pick(hb, 0), wu[32 + 4 * q + 0], au0);
      au1 = dot2f(pick(hb, 1), wu[32 + 4 * q + 1], au1);
      au0 = dot2f(pick(hb, 2), wu[32 + 4 * q + 2], au0);
      au1 = dot2f(pick(hb, 3), wu[32 + 4 * q + 3], au1);
      nr0 = dot2f(pick(xb, 0), wr[4 * q + 0], nr0);
      nr1 = dot2f(pick(xb, 1), wr[4 * q + 1], nr1);
      nr0 = dot2f(pick(xb, 2), wr[4 * q + 2], nr0);
      nr1 = dot2f(pick(xb, 3), wr[4 * q + 3], nr1);
      nu0 = dot2f(pick(xb, 0), wu[4 * q + 0], nu0);
      nu1 = dot2f(pick(xb, 1), wu[4 * q + 1], nu1);
      nu0 = dot2f(pick(xb, 2), wu[4 * q + 2], nu0);
      nu1 = dot2f(pick(xb, 3), wu[4 * q + 3], nu1);
    }
    const float r = sigmoidf_(ar0 + ar1);
    const float u = sigmoidf_(au0 + au1);

    // Stage r*h for the candidate's h-part.
    vrh[d] = (half_t)(r * h);
    asm volatile("" ::: "memory");

    // ---- Phase B: candidate h-part + next step's candidate x-part.
    float ac0 = acx, ac1 = 0.f;
    float nc0 = bcd, nc1 = 0.f;
#pragma unroll
    for (int q = 0; q < 8; ++q) {
      const h8 rb = pr[q];
      const h8 xb = px[q];
      ac0 = dot2f(pick(rb, 0), wc[32 + 4 * q + 0], ac0);
      ac1 = dot2f(pick(rb, 1), wc[32 + 4 * q + 1], ac1);
      ac0 = dot2f(pick(rb, 2), wc[32 + 4 * q + 2], ac0);
      ac1 = dot2f(pick(rb, 3), wc[32 + 4 * q + 3], ac1);
      nc0 = dot2f(pick(xb, 0), wc[4 * q + 0], nc0);
      nc1 = dot2f(pick(xb, 1), wc[4 * q + 1], nc1);
      nc0 = dot2f(pick(xb, 2), wc[4 * q + 2], nc0);
      nc1 = dot2f(pick(xb, 3), wc[4 * q + 3], nc1);
    }
    const float c = tanhf_(ac0 + ac1);

    const float ua = an * u;
    h = fmaf(ua, c - h, h);  // (1-ua)*h + ua*c
    orow[t * D_ + d] = h;

    arx = nr0 + nr1;
    aux = nu0 + nu1;
    acx = nc0 + nc1;
    xn = xn2;
    an = an1;
  }

  // Zero-fill outputs past this row's sequence length.
  for (int t = L; t < T_; ++t) {
    orow[t * D_ + d] = 0.0f;
  }
}

extern "C" void kernel_launch(void* const* d_in, const int* in_sizes, int n_in,
                              void* d_out, int out_size, void* d_ws, size_t ws_size,
                              hipStream_t stream) {
  (void)in_sizes; (void)n_in; (void)d_ws; (void)ws_size; (void)out_size;
  const float* X  = (const float*)d_in[0];
  const int*   SL = (const int*)d_in[1];
  const float* A  = (const float*)d_in[2];
  const float* Wg = (const float*)d_in[3];
  const float* bg = (const float*)d_in[4];
  const float* Wc = (const float*)d_in[5];
  const float* bc = (const float*)d_in[6];
  float* O = (float*)d_out;

  augru_pipe<<<NBLK, BLK, 0, stream>>>(X, SL, A, Wg, bg, Wc, bc, O);
}